// Round 13
// baseline (68.208 us; speedup 1.0000x reference)
//
#include <hip/hip_runtime.h>
#include <cstdint>

#define DEVINL __device__ __forceinline__

typedef __attribute__((ext_vector_type(8))) short bf16x8;
typedef __attribute__((ext_vector_type(4))) float f32x4;
typedef __attribute__((ext_vector_type(8))) unsigned short u16x8;
typedef unsigned short u16;
typedef unsigned int u32;

#define MFMA16(a, b, c) __builtin_amdgcn_mfma_f32_16x16x32_bf16(a, b, c, 0, 0, 0)

#define LOG2E 1.4426950408889634f
#define LN2 0.69314718055994531f

DEVINL u16 f2bf(float x) {
  u32 u = __builtin_bit_cast(u32, x);
  u += 0x7FFFu + ((u >> 16) & 1u);
  return (u16)(u >> 16);
}
DEVINL float exp2fast(float x) {  // v_exp_f32 IS 2^x
  float r;
  asm("v_exp_f32 %0, %1" : "=v"(r) : "v"(x));
  return r;
}
DEVINL void gload_lds16(const void* g, void* l) {
  __builtin_amdgcn_global_load_lds(
      (const __attribute__((address_space(1))) unsigned int*)g,
      (__attribute__((address_space(3))) unsigned int*)l, 16, 0, 0);
}

// ---------------- fused prologue: f32->bf16 converts + efq ------------------
__global__ __launch_bounds__(256) void k_prep(const float* __restrict__ x,
                                              const float* __restrict__ Wq,
                                              const float* __restrict__ Wk,
                                              const float* __restrict__ Wv,
                                              const float* __restrict__ Wo,
                                              const float* __restrict__ ent,
                                              u16* __restrict__ xb,
                                              u16* __restrict__ Wb,
                                              u16* __restrict__ Wob,
                                              float* __restrict__ efq) {
  const int bid = blockIdx.x;
  if (bid < 3072) {
    const float* src;
    u16* dst;
    int base;
    if (bid < 1024)      { src = x;  dst = xb;            base = bid; }
    else if (bid < 1536) { src = Wq; dst = Wb;            base = bid - 1024; }
    else if (bid < 2048) { src = Wk; dst = Wb + (1u<<20); base = bid - 1536; }
    else if (bid < 2560) { src = Wv; dst = Wb + (2u<<20); base = bid - 2048; }
    else                 { src = Wo; dst = Wob;           base = bid - 2560; }
    int i = base * 256 + threadIdx.x;
    const float4* s4 = (const float4*)src;
    float4 a = s4[2 * i], b = s4[2 * i + 1];
    u16x8 o;
    o[0] = f2bf(a.x); o[1] = f2bf(a.y); o[2] = f2bf(a.z); o[3] = f2bf(a.w);
    o[4] = f2bf(b.x); o[5] = f2bf(b.y); o[6] = f2bf(b.z); o[7] = f2bf(b.w);
    *(u16x8*)(dst + 8 * i) = o;
  } else {
    int i = (bid - 3072) * 256 + threadIdx.x;
    float e = ent[i];
    float Et = 1.f / (1.f + __expf(-5.f * (e - 0.3f)));
    efq[i] = __expf(-(5.f * Et - 0.3f * e));
  }
}

// ---------------- tiled bf16 GEMM, C = A * B^T, BK=64, dbuf LDS, 2-phase -----
// 1D grid, XCD-bijective swizzle. M fixed = 2048.
// MODE 0 (BM=64,BN=128): QKV epilogues (Q*0.125*log2e; K + egk; V -> Vt).
// MODE 1: f32 store to Cout (N=1024).
template <int BM, int BN, int NDIM, int MODE>
__global__ __launch_bounds__(256) void k_gemm(const u16* __restrict__ A,
                                              const u16* __restrict__ Bw,
                                              int Kdim, u16* __restrict__ Qo,
                                              u16* __restrict__ Ko,
                                              u16* __restrict__ Vt,
                                              float* __restrict__ egk_out,
                                              float* __restrict__ Cout) {
  constexpr int MT = BM / 32, NT = BN / 32;
  constexpr int MB = 2048 / BM, NB = NDIM / BN;
  constexpr int CPX = MB * NB / 8;
  __shared__ __align__(16) u16 SM[2][(BM + BN) * 64];
  const int t = threadIdx.x;
  const int lb = (blockIdx.x & 7) * CPX + (blockIdx.x >> 3);
  const int m0 = (lb % MB) * BM, n0 = (lb / MB) * BN;
  const int lane = t & 63, w = t >> 6;
  const int wr = w >> 1, wc = w & 1, lm = lane & 15, lg = lane >> 4;
  const int rs = t >> 3, cs = t & 7;
  f32x4 acc[MT][NT] = {};

#define GSTAGE(buf, kt)                                                        \
  {                                                                            \
    u16* As_ = SM[buf];                                                        \
    u16* Bs_ = SM[buf] + BM * 64;                                              \
    _Pragma("unroll") for (int i = 0; i < BM / 32; ++i) {                      \
      int rr = rs + 32 * i;                                                    \
      gload_lds16(A + (size_t)(m0 + rr) * Kdim + (kt) + ((cs ^ (rr & 7)) * 8), \
                  (char*)As_ + t * 16 + i * 4096);                             \
    }                                                                          \
    _Pragma("unroll") for (int i = 0; i < BN / 32; ++i) {                      \
      int rr = rs + 32 * i;                                                    \
      gload_lds16(Bw + (size_t)(n0 + rr) * Kdim + (kt) + ((cs ^ (rr & 7)) * 8),\
                  (char*)Bs_ + t * 16 + i * 4096);                             \
    }                                                                          \
  }

  GSTAGE(0, 0);
  __syncthreads();
  const int nk = Kdim >> 6;
  for (int ki = 0; ki < nk; ++ki) {
    const int cur = ki & 1;
    if (ki + 1 < nk) GSTAGE(cur ^ 1, (ki + 1) * 64);
    const u16* As = SM[cur];
    const u16* Bs = SM[cur] + BM * 64;
#pragma unroll
    for (int ks = 0; ks < 2; ++ks) {
      bf16x8 af[MT], bfr[NT];
#pragma unroll
      for (int mt = 0; mt < MT; ++mt) {
        int row = wr * (BM / 2) + mt * 16 + lm;
        af[mt] = *(const bf16x8*)((const char*)As + row * 128 +
                                  (((ks * 4 + lg) ^ (row & 7)) << 4));
      }
#pragma unroll
      for (int nt = 0; nt < NT; ++nt) {
        int row = wc * (BN / 2) + nt * 16 + lm;
        bfr[nt] = *(const bf16x8*)((const char*)Bs + row * 128 +
                                   (((ks * 4 + lg) ^ (row & 7)) << 4));
      }
#pragma unroll
      for (int mt = 0; mt < MT; ++mt)
#pragma unroll
        for (int nt = 0; nt < NT; ++nt)
          acc[mt][nt] = MFMA16(af[mt], bfr[nt], acc[mt][nt]);
    }
    __syncthreads();
  }
#undef GSTAGE

  if (MODE == 1) {
#pragma unroll
    for (int mt = 0; mt < MT; ++mt)
#pragma unroll
      for (int nt = 0; nt < NT; ++nt)
#pragma unroll
        for (int r = 0; r < 4; ++r) {
          int m = m0 + wr * (BM / 2) + mt * 16 + lg * 4 + r;
          int n = n0 + wc * (BN / 2) + nt * 16 + lm;
          Cout[(size_t)m * 1024 + n] = acc[mt][nt][r];
        }
    return;
  }

  // MODE 0 epilogue (BM=64, BN=128): region by n0; one head per wave-column.
  const int region = n0 >> 10;  // 0=Q 1=K 2=V
  const int b = m0 >> 10, s0 = m0 & 1023;
  if (region < 2) {
    u16* dst = region == 0 ? Qo : Ko;
    const float scl = region == 0 ? 0.125f * LOG2E : 1.f;  // Q in log2 domain
#pragma unroll
    for (int mt = 0; mt < MT; ++mt)
#pragma unroll
      for (int nt = 0; nt < NT; ++nt)
#pragma unroll
        for (int r = 0; r < 4; ++r) {
          int m = m0 + wr * (BM / 2) + mt * 16 + lg * 4 + r;
          int n = n0 + wc * (BN / 2) + nt * 16 + lm;
          int e = n & 1023, h = e >> 6, d = e & 63;
          dst[(size_t)(((b << 4) + h) * 1024 + (m & 1023)) * 64 + d] =
              f2bf(acc[mt][nt][r] * scl);
        }
    if (region == 1) {
      // egk = exp(-1.4*min(sum_d K^2/64, 2)); wave-column wc = one head
      int hh = ((n0 - 1024) >> 6) + wc;
#pragma unroll
      for (int mt = 0; mt < MT; ++mt)
#pragma unroll
        for (int r = 0; r < 4; ++r) {
          float ss = 0.f;
#pragma unroll
          for (int nt = 0; nt < NT; ++nt) ss += acc[mt][nt][r] * acc[mt][nt][r];
          ss += __shfl_xor(ss, 1);
          ss += __shfl_xor(ss, 2);
          ss += __shfl_xor(ss, 4);
          ss += __shfl_xor(ss, 8);
          if (lm == 0) {
            int s = s0 + wr * (BM / 2) + mt * 16 + lg * 4 + r;
            float g = 1.4f * fminf(ss * (1.f / 64.f), 2.f);
            egk_out[(size_t)(((b << 4) + hh)) * 1024 + s] = __expf(-g);
          }
        }
    }
  } else {
    // V: transpose via LDS, tile[64 d][64 m] swizzled; one head per wc half
    u16* tile = SM[0];
#pragma unroll
    for (int half = 0; half < 2; ++half) {
      if (wc == half) {
#pragma unroll
        for (int mt = 0; mt < MT; ++mt)
#pragma unroll
          for (int nt = 0; nt < NT; ++nt)
#pragma unroll
            for (int r = 0; r < 4; ++r) {
              int d = nt * 16 + lm;
              int mloc = wr * (BM / 2) + mt * 16 + lg * 4 + r;
              tile[d * 64 + (mloc ^ ((d & 7) << 3))] = f2bf(acc[mt][nt][r]);
            }
      }
      __syncthreads();
      int hh = ((n0 - 2048) >> 6) + half;
#pragma unroll
      for (int j = 0; j < 2; ++j) {
        int dd = (t >> 3) + 32 * j, mc = t & 7;
        u16x8 v = *(const u16x8*)&tile[dd * 64 + ((mc * 8) ^ ((dd & 7) << 3))];
        *(u16x8*)(Vt + ((size_t)(((b << 4) + hh) * 64 + dd)) * 1024 + s0 + mc * 8) = v;
      }
      __syncthreads();
    }
  }
}

// ---------------- K-split gated flash attention + entropy --------------------
// grid 1024 (XCD-swizzled); 4 waves = 2 q-tiles x 2 k-halves; 32 q/block.
// Waves split k by 64-tile parity; shared single-buffered K/V pair staging;
// exact defer-max merge at the end. 40 KB LDS -> 4 blocks/CU = 4 waves/SIMD.
__global__ __launch_bounds__(256, 4) void k_attn2(const u16* __restrict__ Q,
                                                  const u16* __restrict__ Kt,
                                                  const u16* __restrict__ Vt,
                                                  const float* __restrict__ efq,
                                                  const float* __restrict__ egk,
                                                  u16* __restrict__ Ob,
                                                  float* __restrict__ Sst) {
  __shared__ __align__(16) u16 Ks[128 * 64];    // 16 KB: rows = k0..k0+127
  __shared__ __align__(16) u16 Vs[2][64 * 64];  // 16 KB: [khalf][d][kc], swizzled
  __shared__ __align__(16) u32 Ps[4][16][32];   // 8 KB per-wave P pairs
  const int i = blockIdx.x;
  const int lb = ((i & 7) << 7) | (i >> 3);  // XCD-bijective: 1024 = 8*128
  const int bh = lb >> 5, qpb = lb & 31;
  const int t = threadIdx.x, lane = t & 63, w = t >> 6;
  const int lm = lane & 15, lg = lane >> 4;
  const int b = bh >> 4, h = bh & 15;
  const size_t bhS = (size_t)bh << 10;
  const int khalf = w & 1, qt = w >> 1;
  const int qb = qpb * 32 + qt * 16;

  // stage a PAIR of 64-k tiles (k0..k0+127): K rows 0..127; V split by half
  auto stage = [&](int k0) {
    int rowK = t >> 3, cK = t & 7;
#pragma unroll
    for (int i2 = 0; i2 < 4; ++i2) {
      int rr = rowK + 32 * i2;
      gload_lds16(Kt + (bhS + k0 + rr) * 64 + ((cK ^ (rr & 7)) * 8),
                  (char*)Ks + t * 16 + i2 * 4096);
    }
#pragma unroll
    for (int half = 0; half < 2; ++half)
#pragma unroll
      for (int i2 = 0; i2 < 2; ++i2) {
        int dd = rowK + 32 * i2;
        gload_lds16(Vt + ((size_t)bh * 64 + dd) * 1024 + k0 + half * 64 +
                        ((cK ^ (dd & 7)) * 8),
                    (char*)Vs[half] + t * 16 + i2 * 4096);
      }
  };

  bf16x8 qf[2];
#pragma unroll
  for (int ks = 0; ks < 2; ++ks)
    qf[ks] = *(const bf16x8*)(Q + (bhS + qb + lm) * 64 + ks * 32 + lg * 8);
  const float efql = efq[bhS + qb + lm];

  f32x4 Oacc[4] = {};
  float m_r = -1e30f, l_r = 0.f, W_r = 0.f;  // m,W in log2 units

  for (int jt = 0; jt < 8; ++jt) {
    stage(jt * 128);
    __syncthreads();  // DMA drained (vmcnt 0) + all waves ready

    const int kbase = khalf * 64;  // this wave's tile within the pair
    f32x4 egN[4];
#pragma unroll
    for (int nt = 0; nt < 4; ++nt)
      egN[nt] = *(const f32x4*)&egk[bhS + jt * 128 + kbase + nt * 16 + lg * 4];

    f32x4 c_[4];
    __builtin_amdgcn_s_setprio(1);
#pragma unroll
    for (int nt = 0; nt < 4; ++nt) {
      c_[nt] = (f32x4){0.f, 0.f, 0.f, 0.f};
#pragma unroll
      for (int ks = 0; ks < 2; ++ks) {
        int row = nt * 16 + lm;
        int byo = (((ks * 4 + lg) ^ (row & 7)) << 4);
        bf16x8 kb =
            *(const bf16x8*)((const char*)Ks + (kbase + row) * 128 + byo);
        c_[nt] = MFMA16(kb, qf[ks], c_[nt]);
      }
    }
    __builtin_amdgcn_s_setprio(0);

    // gate: v = c - x*(1.4426950 + x*(-0.72134752 + 0.37*x))  [no trans ops]
    float v_[4][4];
    float lmax = -3e38f;
#pragma unroll
    for (int nt = 0; nt < 4; ++nt) {
      f32x4 eg = egN[nt];
#pragma unroll
      for (int r = 0; r < 4; ++r) {
        float xg = efql * eg[r];
        float t3 = fmaf(xg, 0.37f, -0.72134752f);
        float lp = xg * fmaf(xg, t3, 1.4426950f);
        v_[nt][r] = c_[nt][r] - lp;
      }
      lmax = fmaxf(fmaxf(lmax, v_[nt][0]),
                   fmaxf(fmaxf(v_[nt][1], v_[nt][2]), v_[nt][3]));
    }
    lmax = fmaxf(lmax, __shfl_xor(lmax, 16));
    lmax = fmaxf(lmax, __shfl_xor(lmax, 32));

    if (__any(lmax > m_r + 7.2134752f)) {  // defer-max (T13), 5 nat in log2
      float mn = fmaxf(m_r, lmax);
      float dd = m_r - mn;
      float sc = exp2fast(dd);
      W_r = sc * (W_r + dd * l_r);
      l_r *= sc;
      m_r = mn;
      float scO[4];
#pragma unroll
      for (int r = 0; r < 4; ++r) scO[r] = __shfl(sc, (lane & 48) | (lg * 4 + r));
#pragma unroll
      for (int dt = 0; dt < 4; ++dt)
#pragma unroll
        for (int r = 0; r < 4; ++r) Oacc[dt][r] *= scO[r];
    }

    float psumR[4] = {0.f, 0.f, 0.f, 0.f}, wsumR[4] = {0.f, 0.f, 0.f, 0.f};
    u32 pw[8];
#pragma unroll
    for (int nt = 0; nt < 4; ++nt) {
      float p_[4];
#pragma unroll
      for (int r = 0; r < 4; ++r) {
        float sh = v_[nt][r] - m_r;
        float p = exp2fast(sh);
        p_[r] = p;
        psumR[r] += p;
        wsumR[r] = fmaf(p, sh, wsumR[r]);
      }
      asm("v_cvt_pk_bf16_f32 %0, %1, %2" : "=v"(pw[nt*2+0]) : "v"(p_[0]), "v"(p_[1]));
      asm("v_cvt_pk_bf16_f32 %0, %1, %2" : "=v"(pw[nt*2+1]) : "v"(p_[2]), "v"(p_[3]));
    }
    float psum = (psumR[0] + psumR[1]) + (psumR[2] + psumR[3]);
    float wsum = (wsumR[0] + wsumR[1]) + (wsumR[2] + wsumR[3]);
    psum += __shfl_xor(psum, 16);
    psum += __shfl_xor(psum, 32);
    wsum += __shfl_xor(wsum, 16);
    wsum += __shfl_xor(wsum, 32);
    l_r += psum;
    W_r += wsum;

    u32* prow = &Ps[w][lm][0];
    const int sw = (lm & 7) << 2;
#pragma unroll
    for (int nt = 0; nt < 4; ++nt) {
      int idx = (nt * 8 + lg * 2) ^ sw;
      uint2 pr;
      pr.x = pw[nt * 2 + 0];
      pr.y = pw[nt * 2 + 1];
      *(uint2*)(prow + idx) = pr;
    }

    bf16x8 pa[2];
#pragma unroll
    for (int ks = 0; ks < 2; ++ks) {
      int idx = (ks * 16 + lg * 4) ^ sw;
      pa[ks] = *(const bf16x8*)(prow + idx);
    }
    __builtin_amdgcn_s_setprio(1);
#pragma unroll
    for (int dt = 0; dt < 4; ++dt) {
#pragma unroll
      for (int ks = 0; ks < 2; ++ks) {
        int row = dt * 16 + lm;
        int byo = (((ks * 4 + lg) ^ (row & 7)) << 4);
        bf16x8 vb =
            *(const bf16x8*)((const char*)Vs[khalf] + row * 128 + byo);
        Oacc[dt] = MFMA16(pa[ks], vb, Oacc[dt]);
      }
    }
    __builtin_amdgcn_s_setprio(0);
    __syncthreads();  // all waves done reading this pair before next stage
  }

  // ===== merge the two k-halves (exact defer-max algebra), then write =====
  // LDS reuse (Ks region): per pair qt: O[16][64] j-major + m[16]+l[16]+W[16]
  float* mrg = (float*)Ks + qt * 1088;
  if (khalf == 1) {
#pragma unroll
    for (int dt = 0; dt < 4; ++dt)
#pragma unroll
      for (int r = 0; r < 4; ++r) mrg[(dt * 4 + r) * 64 + lane] = Oacc[dt][r];
    if (lg == 0) {
      mrg[1024 + lm] = m_r;
      mrg[1040 + lm] = l_r;
      mrg[1056 + lm] = W_r;
    }
  }
  __syncthreads();
  if (khalf == 0) {
    float m1 = mrg[1024 + lm], l1 = mrg[1040 + lm], W1 = mrg[1056 + lm];
    float mn = fmaxf(m_r, m1);
    float s0 = exp2fast(m_r - mn), s1 = exp2fast(m1 - mn);
    float l = l_r * s0 + l1 * s1;
    float W = s0 * (W_r + (m_r - mn) * l_r) + s1 * (W1 + (m1 - mn) * l1);
    float invl = 1.f / l;
    float entv = __logf(l) - (W * LN2) * invl;
    float s0q[4], s1q[4], invq[4];
#pragma unroll
    for (int r = 0; r < 4; ++r) {
      int src = (lane & 48) | (lg * 4 + r);
      s0q[r] = __shfl(s0, src);
      s1q[r] = __shfl(s1, src);
      invq[r] = __shfl(invl, src);
    }
#pragma unroll
    for (int dt = 0; dt < 4; ++dt)
#pragma unroll
      for (int r = 0; r < 4; ++r) {
        float o1 = mrg[(dt * 4 + r) * 64 + lane];
        float o = (Oacc[dt][r] * s0q[r] + o1 * s1q[r]) * invq[r];
        int srow = qb + lg * 4 + r;
        int col = h * 64 + dt * 16 + lm;
        Ob[(size_t)(b * 1024 + srow) * 1024 + col] = f2bf(o);
      }
    if (lg == 0) Sst[bhS + qb + lm] = entv;
  }
}

// ---------------- workspace layout (bytes) ----------------
static constexpr size_t OFF_XB = 0;
static constexpr size_t OFF_WB = 4ull << 20;
static constexpr size_t OFF_Q = 10ull << 20;
static constexpr size_t OFF_K = 14ull << 20;
static constexpr size_t OFF_OB = 18ull << 20;
static constexpr size_t OFF_VT = 22ull << 20;
static constexpr size_t OFF_WOB = 26ull << 20;
static constexpr size_t OFF_FQ = 28ull << 20;
static constexpr size_t OFF_GK = (28ull << 20) + (128ull << 10);

extern "C" void kernel_launch(void* const* d_in, const int* in_sizes, int n_in,
                              void* d_out, int out_size, void* d_ws, size_t ws_size,
                              hipStream_t stream) {
  const float* x = (const float*)d_in[0];
  const float* ent = (const float*)d_in[1];
  const float* Wq = (const float*)d_in[2];
  const float* Wk = (const float*)d_in[3];
  const float* Wv = (const float*)d_in[4];
  const float* Wo = (const float*)d_in[5];
  (void)in_sizes; (void)n_in; (void)out_size; (void)ws_size;

  char* ws = (char*)d_ws;
  u16* xb = (u16*)(ws + OFF_XB);
  u16* Wb = (u16*)(ws + OFF_WB);
  u16* Qb = (u16*)(ws + OFF_Q);
  u16* Kb = (u16*)(ws + OFF_K);
  u16* Ob = (u16*)(ws + OFF_OB);
  u16* Vtb = (u16*)(ws + OFF_VT);
  u16* Wob = (u16*)(ws + OFF_WOB);
  float* efqd = (float*)(ws + OFF_FQ);
  float* egkd = (float*)(ws + OFF_GK);
  float* outp = (float*)d_out;
  float* Sst = outp + 2u * 1024u * 1024u;

  k_prep<<<3200, 256, 0, stream>>>(x, Wq, Wk, Wv, Wo, ent, xb, Wb, Wob, efqd);

  k_gemm<64, 128, 3072, 0><<<768, 256, 0, stream>>>(xb, Wb, 1024, Qb, Kb, Vtb,
                                                    egkd, nullptr);

  k_attn2<<<1024, 256, 0, stream>>>(Qb, Kb, Vtb, efqd, egkd, Ob, Sst);

  k_gemm<64, 64, 1024, 1><<<512, 256, 0, stream>>>(Ob, Wob, 1024, nullptr, nullptr,
                                                   nullptr, nullptr, outp);
}

// Round 14
// 66.701 us; speedup vs baseline: 1.0226x; 1.0226x over previous
//
#include <hip/hip_runtime.h>
#include <cstdint>

#define DEVINL __device__ __forceinline__

typedef __attribute__((ext_vector_type(8))) short bf16x8;
typedef __attribute__((ext_vector_type(4))) float f32x4;
typedef __attribute__((ext_vector_type(8))) unsigned short u16x8;
typedef unsigned short u16;
typedef unsigned int u32;

#define MFMA16(a, b, c) __builtin_amdgcn_mfma_f32_16x16x32_bf16(a, b, c, 0, 0, 0)

#define LOG2E 1.4426950408889634f
#define LN2 0.69314718055994531f

DEVINL u16 f2bf(float x) {
  u32 u = __builtin_bit_cast(u32, x);
  u += 0x7FFFu + ((u >> 16) & 1u);
  return (u16)(u >> 16);
}
DEVINL float exp2fast(float x) {  // v_exp_f32 IS 2^x
  float r;
  asm("v_exp_f32 %0, %1" : "=v"(r) : "v"(x));
  return r;
}
DEVINL void gload_lds16(const void* g, void* l) {
  __builtin_amdgcn_global_load_lds(
      (const __attribute__((address_space(1))) unsigned int*)g,
      (__attribute__((address_space(3))) unsigned int*)l, 16, 0, 0);
}

// ---------------- fused prologue: f32->bf16 converts ------------------------
__global__ __launch_bounds__(256) void k_prep(const float* __restrict__ x,
                                              const float* __restrict__ Wq,
                                              const float* __restrict__ Wk,
                                              const float* __restrict__ Wv,
                                              const float* __restrict__ Wo,
                                              u16* __restrict__ xb,
                                              u16* __restrict__ Wb,
                                              u16* __restrict__ Wob) {
  const int bid = blockIdx.x;
  const float* src;
  u16* dst;
  int base;
  if (bid < 1024)      { src = x;  dst = xb;            base = bid; }
  else if (bid < 1536) { src = Wq; dst = Wb;            base = bid - 1024; }
  else if (bid < 2048) { src = Wk; dst = Wb + (1u<<20); base = bid - 1536; }
  else if (bid < 2560) { src = Wv; dst = Wb + (2u<<20); base = bid - 2048; }
  else                 { src = Wo; dst = Wob;           base = bid - 2560; }
  int i = base * 256 + threadIdx.x;
  const float4* s4 = (const float4*)src;
  float4 a = s4[2 * i], b = s4[2 * i + 1];
  u16x8 o;
  o[0] = f2bf(a.x); o[1] = f2bf(a.y); o[2] = f2bf(a.z); o[3] = f2bf(a.w);
  o[4] = f2bf(b.x); o[5] = f2bf(b.y); o[6] = f2bf(b.z); o[7] = f2bf(b.w);
  *(u16x8*)(dst + 8 * i) = o;
}

// ---------------- tiled bf16 GEMM, C = A * B^T, BK=64, dbuf LDS, 2-phase -----
// 1D grid, XCD-bijective swizzle. M fixed = 2048.
// MODE 0 (BM=64,BN=128): QKV epilogues (Q*0.125*log2e; K + egk; V -> Vt).
// MODE 1: f32 store to Cout (N=1024).
template <int BM, int BN, int NDIM, int MODE>
__global__ __launch_bounds__(256) void k_gemm(const u16* __restrict__ A,
                                              const u16* __restrict__ Bw,
                                              int Kdim, u16* __restrict__ Qo,
                                              u16* __restrict__ Ko,
                                              u16* __restrict__ Vt,
                                              float* __restrict__ egk_out,
                                              float* __restrict__ Cout) {
  constexpr int MT = BM / 32, NT = BN / 32;
  constexpr int MB = 2048 / BM, NB = NDIM / BN;
  constexpr int CPX = MB * NB / 8;
  __shared__ __align__(16) u16 SM[2][(BM + BN) * 64];
  const int t = threadIdx.x;
  const int lb = (blockIdx.x & 7) * CPX + (blockIdx.x >> 3);
  const int m0 = (lb % MB) * BM, n0 = (lb / MB) * BN;
  const int lane = t & 63, w = t >> 6;
  const int wr = w >> 1, wc = w & 1, lm = lane & 15, lg = lane >> 4;
  const int rs = t >> 3, cs = t & 7;
  f32x4 acc[MT][NT] = {};

#define GSTAGE(buf, kt)                                                        \
  {                                                                            \
    u16* As_ = SM[buf];                                                        \
    u16* Bs_ = SM[buf] + BM * 64;                                              \
    _Pragma("unroll") for (int i = 0; i < BM / 32; ++i) {                      \
      int rr = rs + 32 * i;                                                    \
      gload_lds16(A + (size_t)(m0 + rr) * Kdim + (kt) + ((cs ^ (rr & 7)) * 8), \
                  (char*)As_ + t * 16 + i * 4096);                             \
    }                                                                          \
    _Pragma("unroll") for (int i = 0; i < BN / 32; ++i) {                      \
      int rr = rs + 32 * i;                                                    \
      gload_lds16(Bw + (size_t)(n0 + rr) * Kdim + (kt) + ((cs ^ (rr & 7)) * 8),\
                  (char*)Bs_ + t * 16 + i * 4096);                             \
    }                                                                          \
  }

  GSTAGE(0, 0);
  __syncthreads();
  const int nk = Kdim >> 6;
  for (int ki = 0; ki < nk; ++ki) {
    const int cur = ki & 1;
    if (ki + 1 < nk) GSTAGE(cur ^ 1, (ki + 1) * 64);
    const u16* As = SM[cur];
    const u16* Bs = SM[cur] + BM * 64;
#pragma unroll
    for (int ks = 0; ks < 2; ++ks) {
      bf16x8 af[MT], bfr[NT];
#pragma unroll
      for (int mt = 0; mt < MT; ++mt) {
        int row = wr * (BM / 2) + mt * 16 + lm;
        af[mt] = *(const bf16x8*)((const char*)As + row * 128 +
                                  (((ks * 4 + lg) ^ (row & 7)) << 4));
      }
#pragma unroll
      for (int nt = 0; nt < NT; ++nt) {
        int row = wc * (BN / 2) + nt * 16 + lm;
        bfr[nt] = *(const bf16x8*)((const char*)Bs + row * 128 +
                                   (((ks * 4 + lg) ^ (row & 7)) << 4));
      }
#pragma unroll
      for (int mt = 0; mt < MT; ++mt)
#pragma unroll
        for (int nt = 0; nt < NT; ++nt)
          acc[mt][nt] = MFMA16(af[mt], bfr[nt], acc[mt][nt]);
    }
    __syncthreads();
  }
#undef GSTAGE

  if (MODE == 1) {
#pragma unroll
    for (int mt = 0; mt < MT; ++mt)
#pragma unroll
      for (int nt = 0; nt < NT; ++nt)
#pragma unroll
        for (int r = 0; r < 4; ++r) {
          int m = m0 + wr * (BM / 2) + mt * 16 + lg * 4 + r;
          int n = n0 + wc * (BN / 2) + nt * 16 + lm;
          Cout[(size_t)m * 1024 + n] = acc[mt][nt][r];
        }
    return;
  }

  // MODE 0 epilogue (BM=64, BN=128): region by n0; one head per wave-column.
  const int region = n0 >> 10;  // 0=Q 1=K 2=V
  const int b = m0 >> 10, s0 = m0 & 1023;
  if (region < 2) {
    u16* dst = region == 0 ? Qo : Ko;
    const float scl = region == 0 ? 0.125f * LOG2E : 1.f;  // Q in log2 domain
#pragma unroll
    for (int mt = 0; mt < MT; ++mt)
#pragma unroll
      for (int nt = 0; nt < NT; ++nt)
#pragma unroll
        for (int r = 0; r < 4; ++r) {
          int m = m0 + wr * (BM / 2) + mt * 16 + lg * 4 + r;
          int n = n0 + wc * (BN / 2) + nt * 16 + lm;
          int e = n & 1023, h = e >> 6, d = e & 63;
          dst[(size_t)(((b << 4) + h) * 1024 + (m & 1023)) * 64 + d] =
              f2bf(acc[mt][nt][r] * scl);
        }
    if (region == 1) {
      // egk = exp(-1.4*min(sum_d K^2/64, 2)); wave-column wc = one head
      int hh = ((n0 - 1024) >> 6) + wc;
#pragma unroll
      for (int mt = 0; mt < MT; ++mt)
#pragma unroll
        for (int r = 0; r < 4; ++r) {
          float ss = 0.f;
#pragma unroll
          for (int nt = 0; nt < NT; ++nt) ss += acc[mt][nt][r] * acc[mt][nt][r];
          ss += __shfl_xor(ss, 1);
          ss += __shfl_xor(ss, 2);
          ss += __shfl_xor(ss, 4);
          ss += __shfl_xor(ss, 8);
          if (lm == 0) {
            int s = s0 + wr * (BM / 2) + mt * 16 + lg * 4 + r;
            float g = 1.4f * fminf(ss * (1.f / 64.f), 2.f);
            egk_out[(size_t)(((b << 4) + hh)) * 1024 + s] = __expf(-g);
          }
        }
    }
  } else {
    // V: transpose via LDS, tile[64 d][64 m] swizzled; one head per wc half
    u16* tile = SM[0];
#pragma unroll
    for (int half = 0; half < 2; ++half) {
      if (wc == half) {
#pragma unroll
        for (int mt = 0; mt < MT; ++mt)
#pragma unroll
          for (int nt = 0; nt < NT; ++nt)
#pragma unroll
            for (int r = 0; r < 4; ++r) {
              int d = nt * 16 + lm;
              int mloc = wr * (BM / 2) + mt * 16 + lg * 4 + r;
              tile[d * 64 + (mloc ^ ((d & 7) << 3))] = f2bf(acc[mt][nt][r]);
            }
      }
      __syncthreads();
      int hh = ((n0 - 2048) >> 6) + half;
#pragma unroll
      for (int j = 0; j < 2; ++j) {
        int dd = (t >> 3) + 32 * j, mc = t & 7;
        u16x8 v = *(const u16x8*)&tile[dd * 64 + ((mc * 8) ^ ((dd & 7) << 3))];
        *(u16x8*)(Vt + ((size_t)(((b << 4) + hh) * 64 + dd)) * 1024 + s0 + mc * 8) = v;
      }
      __syncthreads();
    }
  }
}

// ---------------- fused gated flash attention + entropy (log2 domain) --------
// grid 512 (XCD-swizzled); 4 waves/block, 16 q-rows/wave, KVBLK=128, dbuf LDS.
// Gate: v = c - P3(x), x = efq*egk; efq computed inline from ent (exact same
// math as the old prep branch). P3 = cubic minimax of log2(1+x) on [0,0.41].
__global__ __launch_bounds__(256, 2) void k_attn(const u16* __restrict__ Q,
                                                 const u16* __restrict__ Kt,
                                                 const u16* __restrict__ Vt,
                                                 const float* __restrict__ ent,
                                                 const float* __restrict__ egk,
                                                 u16* __restrict__ Ob,
                                                 float* __restrict__ Sst) {
  __shared__ __align__(16) u16 Ks[2][128 * 64];  // [k][d], swizzled (16KB ea)
  __shared__ __align__(16) u16 Vs[2][64 * 128];  // [d][k], swizzled (16KB ea)
  __shared__ __align__(16) u32 Ps[4][16][64];    // per-wave P pairs (16KB)
  const int i = blockIdx.x;
  const int lb = ((i & 7) << 6) | (i >> 3);  // XCD-bijective: 4 bh per XCD
  const int bh = lb >> 4, qblk = lb & 15;
  const int t = threadIdx.x, lane = t & 63, w = t >> 6;
  const int lm = lane & 15, lg = lane >> 4;
  const int b = bh >> 4, h = bh & 15;
  const size_t bhS = (size_t)bh << 10;
  const int qb = qblk * 64 + w * 16;

#define STAGE(buf, k0)                                                         \
  {                                                                            \
    int rowK = t >> 3, cK = t & 7;                                             \
    int rowV = t >> 4, cV = t & 15;                                            \
    _Pragma("unroll") for (int i2 = 0; i2 < 4; ++i2) {                         \
      int rr = rowK + 32 * i2;                                                 \
      gload_lds16(Kt + (bhS + (k0) + rr) * 64 + ((cK ^ (rr & 7)) * 8),         \
                  (char*)Ks[buf] + t * 16 + i2 * 4096);                        \
      int dd2 = rowV + 16 * i2;                                                \
      gload_lds16(Vt + ((size_t)bh * 64 + dd2) * 1024 + (k0) +                 \
                      ((cV ^ (dd2 & 15)) * 8),                                 \
                  (char*)Vs[buf] + t * 16 + i2 * 4096);                        \
    }                                                                          \
  }

  bf16x8 qf[2];
#pragma unroll
  for (int ks = 0; ks < 2; ++ks)
    qf[ks] = *(const bf16x8*)(Q + (bhS + qb + lm) * 64 + ks * 32 + lg * 8);
  // efq = exp(-(5*sigmoid(5(e-0.3)) - 0.3e)), inline (was k_prep's branch)
  float efql;
  {
    float e = ent[bhS + qb + lm];
    float Et = 1.f / (1.f + __expf(-5.f * (e - 0.3f)));
    efql = __expf(-(5.f * Et - 0.3f * e));
  }

  f32x4 Oacc[4] = {};
  float m_r = -1e30f, l_r = 0.f, W_r = 0.f;  // m,W in log2 units

  STAGE(0, 0);
  f32x4 egN[8];
#pragma unroll
  for (int nt = 0; nt < 8; ++nt)
    egN[nt] = *(const f32x4*)&egk[bhS + nt * 16 + lg * 4];
  __syncthreads();

  for (int kt = 0; kt < 8; ++kt) {
    const int cur = kt & 1;
    if (kt < 7) STAGE(cur ^ 1, (kt + 1) * 128);

    // swapped QK^T: lane owns q = lm; k = nt*16 + lg*4 + r (log2-scaled)
    f32x4 c_[8];
    __builtin_amdgcn_s_setprio(1);
#pragma unroll
    for (int nt = 0; nt < 8; ++nt) {
      c_[nt] = (f32x4){0.f, 0.f, 0.f, 0.f};
#pragma unroll
      for (int ks = 0; ks < 2; ++ks) {
        int row = nt * 16 + lm;
        int byo = (((ks * 4 + lg) ^ (row & 7)) << 4);
        bf16x8 kb = *(const bf16x8*)((const char*)Ks[cur] + row * 128 + byo);
        c_[nt] = MFMA16(kb, qf[ks], c_[nt]);
      }
    }
    __builtin_amdgcn_s_setprio(0);

    // gate: v = c - x*(1.4426950 + x*(-0.72134752 + 0.37*x))  [no trans ops]
    float v_[8][4];
    float lmax = -3e38f;
#pragma unroll
    for (int nt = 0; nt < 8; ++nt) {
      f32x4 eg = egN[nt];
#pragma unroll
      for (int r = 0; r < 4; ++r) {
        float xg = efql * eg[r];
        float t3 = fmaf(xg, 0.37f, -0.72134752f);
        float lp = xg * fmaf(xg, t3, 1.4426950f);
        v_[nt][r] = c_[nt][r] - lp;
      }
      lmax = fmaxf(fmaxf(lmax, v_[nt][0]),
                   fmaxf(fmaxf(v_[nt][1], v_[nt][2]), v_[nt][3]));
    }
    if (kt < 7) {
#pragma unroll
      for (int nt = 0; nt < 8; ++nt)
        egN[nt] = *(const f32x4*)&egk[bhS + (kt + 1) * 128 + nt * 16 + lg * 4];
    }
    lmax = fmaxf(lmax, __shfl_xor(lmax, 16));
    lmax = fmaxf(lmax, __shfl_xor(lmax, 32));

    // defer-max (T13): threshold 5 natural units = 5*log2e in log2 units
    if (__any(lmax > m_r + 7.2134752f)) {
      float mn = fmaxf(m_r, lmax);
      float dd = m_r - mn;
      float sc = exp2fast(dd);
      W_r = sc * (W_r + dd * l_r);
      l_r *= sc;
      m_r = mn;
      float scO[4];
#pragma unroll
      for (int r = 0; r < 4; ++r) scO[r] = __shfl(sc, (lane & 48) | (lg * 4 + r));
#pragma unroll
      for (int dt = 0; dt < 4; ++dt)
#pragma unroll
        for (int r = 0; r < 4; ++r) Oacc[dt][r] *= scO[r];
    }

    // p = exp2(v-m); 4 parallel per-r accumulation chains (ILP), merged below
    float psumR[4] = {0.f, 0.f, 0.f, 0.f}, wsumR[4] = {0.f, 0.f, 0.f, 0.f};
    u32 pw[16];
#pragma unroll
    for (int nt = 0; nt < 8; ++nt) {
      float p_[4];
#pragma unroll
      for (int r = 0; r < 4; ++r) {
        float sh = v_[nt][r] - m_r;
        float p = exp2fast(sh);
        p_[r] = p;
        psumR[r] += p;
        wsumR[r] = fmaf(p, sh, wsumR[r]);
      }
      asm("v_cvt_pk_bf16_f32 %0, %1, %2" : "=v"(pw[nt * 2 + 0]) : "v"(p_[0]), "v"(p_[1]));
      asm("v_cvt_pk_bf16_f32 %0, %1, %2" : "=v"(pw[nt * 2 + 1]) : "v"(p_[2]), "v"(p_[3]));
    }
    float psum = (psumR[0] + psumR[1]) + (psumR[2] + psumR[3]);
    float wsum = (wsumR[0] + wsumR[1]) + (wsumR[2] + wsumR[3]);
    psum += __shfl_xor(psum, 16);
    psum += __shfl_xor(psum, 32);
    wsum += __shfl_xor(wsum, 16);
    wsum += __shfl_xor(wsum, 32);
    l_r += psum;
    W_r += wsum;

    // P -> per-wave LDS (swizzled u32 pairs)
    u32* prow = &Ps[w][lm][0];
    const int sw = (lm & 7) << 2;
#pragma unroll
    for (int nt = 0; nt < 8; ++nt) {
      int idx = (nt * 8 + lg * 2) ^ sw;
      uint2 pr;
      pr.x = pw[nt * 2 + 0];
      pr.y = pw[nt * 2 + 1];
      *(uint2*)(prow + idx) = pr;
    }

    bf16x8 pa[4];
#pragma unroll
    for (int ks = 0; ks < 4; ++ks) {
      int idx = (ks * 16 + lg * 4) ^ sw;
      pa[ks] = *(const bf16x8*)(prow + idx);
    }
    __builtin_amdgcn_s_setprio(1);
#pragma unroll
    for (int dt = 0; dt < 4; ++dt) {
#pragma unroll
      for (int ks = 0; ks < 4; ++ks) {
        int row = dt * 16 + lm;
        int byo = (((ks * 4 + lg) ^ (row & 15)) << 4);
        bf16x8 vb = *(const bf16x8*)((const char*)Vs[cur] + row * 256 + byo);
        Oacc[dt] = MFMA16(pa[ks], vb, Oacc[dt]);
      }
    }
    __builtin_amdgcn_s_setprio(0);
    __syncthreads();  // drains vmcnt(0): next buffer staged & ready
  }

  float invl = 1.f / l_r;
  float entv = __logf(l_r) - (W_r * LN2) * invl;  // W back to natural units
  float invO[4];
#pragma unroll
  for (int r = 0; r < 4; ++r) invO[r] = __shfl(invl, (lane & 48) | (lg * 4 + r));
#pragma unroll
  for (int dt = 0; dt < 4; ++dt)
#pragma unroll
    for (int r = 0; r < 4; ++r) {
      int srow = qb + lg * 4 + r;
      int col = h * 64 + dt * 16 + lm;
      Ob[(size_t)(b * 1024 + srow) * 1024 + col] = f2bf(Oacc[dt][r] * invO[r]);
    }
  if (lg == 0) Sst[bhS + qb + lm] = entv;
#undef STAGE
}

// ---------------- workspace layout (bytes) ----------------
static constexpr size_t OFF_XB = 0;
static constexpr size_t OFF_WB = 4ull << 20;
static constexpr size_t OFF_Q = 10ull << 20;
static constexpr size_t OFF_K = 14ull << 20;
static constexpr size_t OFF_OB = 18ull << 20;
static constexpr size_t OFF_VT = 22ull << 20;
static constexpr size_t OFF_WOB = 26ull << 20;
static constexpr size_t OFF_GK = 28ull << 20;

extern "C" void kernel_launch(void* const* d_in, const int* in_sizes, int n_in,
                              void* d_out, int out_size, void* d_ws, size_t ws_size,
                              hipStream_t stream) {
  const float* x = (const float*)d_in[0];
  const float* ent = (const float*)d_in[1];
  const float* Wq = (const float*)d_in[2];
  const float* Wk = (const float*)d_in[3];
  const float* Wv = (const float*)d_in[4];
  const float* Wo = (const float*)d_in[5];
  (void)in_sizes; (void)n_in; (void)out_size; (void)ws_size;

  char* ws = (char*)d_ws;
  u16* xb = (u16*)(ws + OFF_XB);
  u16* Wb = (u16*)(ws + OFF_WB);
  u16* Qb = (u16*)(ws + OFF_Q);
  u16* Kb = (u16*)(ws + OFF_K);
  u16* Ob = (u16*)(ws + OFF_OB);
  u16* Vtb = (u16*)(ws + OFF_VT);
  u16* Wob = (u16*)(ws + OFF_WOB);
  float* egkd = (float*)(ws + OFF_GK);
  float* outp = (float*)d_out;
  float* Sst = outp + 2u * 1024u * 1024u;

  k_prep<<<3072, 256, 0, stream>>>(x, Wq, Wk, Wv, Wo, xb, Wb, Wob);

  k_gemm<64, 128, 3072, 0><<<768, 256, 0, stream>>>(xb, Wb, 1024, Qb, Kb, Vtb,
                                                    egkd, nullptr);

  k_attn<<<512, 256, 0, stream>>>(Qb, Kb, Vtb, ent, egkd, Ob, Sst);

  k_gemm<64, 64, 1024, 1><<<512, 256, 0, stream>>>(Ob, Wob, 1024, nullptr, nullptr,
                                                   nullptr, nullptr, outp);
}